// Round 8
// baseline (198.713 us; speedup 1.0000x reference)
//
#include <hip/hip_runtime.h>

typedef unsigned short u16;
typedef __attribute__((ext_vector_type(8))) short bf16x8;
typedef __attribute__((ext_vector_type(4))) float f32x4;

// round-to-nearest (ties away): 2 VALU ops
__device__ __forceinline__ u16 f2bf(float f) {
    return (u16)((__float_as_uint(f) + 0x8000u) >> 16);
}

#define N_NODES 2048
#define D_EMB 64
#define P_DIM 32
#define NS_STOPS 512
#define IN_LEN 4131   // 32 + 2048 + 2048 + 3
#define NKT 65        // K-tiles of 64 (2048 es + 2048 dist + 32 pref + 32 pad)

// 16B-chunk XOR swizzle within a tile row (8 chunks of 8 shorts) -- B tiles only
#define SWZ(row, c) ((((row) * 8) + ((c) ^ ((row) & 7))) * 8)

__device__ __forceinline__ void gload16(const u16* g, u16* l) {
    __builtin_amdgcn_global_load_lds((const __attribute__((address_space(1))) void*)g,
                                     (__attribute__((address_space(3))) void*)l, 16, 0, 0);
}

// ---------------- LDS-staged aggpref: 256 blocks x 8 nodes; stop rows staged ONCE ----------------
__global__ __launch_bounds__(256) void k_aggpref(const float* __restrict__ emb, const int* __restrict__ stops,
                                                 const float* __restrict__ lin_l_w, const float* __restrict__ lin_l_b,
                                                 const float* __restrict__ lin_r_w, const float* __restrict__ edge_w,
                                                 float* __restrict__ pref, float* __restrict__ av, float* __restrict__ bv,
                                                 float* __restrict__ keepf) {
    __shared__ float se[NS_STOPS][68];   // 139264 B; 17-word row stride -> conflict-free
    __shared__ int bm[64];
    __shared__ int kl[NS_STOPS];
    __shared__ float nrm[NS_STOPS];
    __shared__ float xiS[8][D_EMB];
    __shared__ float aggS[8][D_EMB];
    __shared__ float niS[8];
    __shared__ int degS[8];
    __shared__ int kiS[8];
    __shared__ int cnt;
    int t = threadIdx.x;
    int i0 = blockIdx.x * 8;
    if (t < 64) bm[t] = 0;
    if (t == 0) cnt = 0;
    if (t < 8) degS[t] = 0;
    ((float*)aggS)[t] = 0.f;
    ((float*)aggS)[t + 256] = 0.f;
    __syncthreads();
    {   // scatter stops into bitmap
        int s0 = stops[t], s1 = stops[t + 256];
        atomicOr(&bm[s0 >> 5], 1 << (s0 & 31));
        atomicOr(&bm[s1 >> 5], 1 << (s1 & 31));
    }
    __syncthreads();
    {   // compact set nodes into kl
        int w = bm[t >> 2];
        int base = (t >> 2) * 32 + (t & 3) * 8;
        #pragma unroll
        for (int e = 0; e < 8; ++e)
            if ((w >> ((t & 3) * 8 + e)) & 1) { int p = atomicAdd(&cnt, 1); kl[p] = base + e; }
    }
    if (t < 8) { int i = i0 + t; kiS[t] = (bm[i >> 5] >> (i & 31)) & 1; }
    {   // load this block's 8 node rows
        int n = t >> 5, d = (t & 31) * 2;
        xiS[n][d]     = emb[(i0 + n) * D_EMB + d];
        xiS[n][d + 1] = emb[(i0 + n) * D_EMB + d + 1];
    }
    __syncthreads();
    int nk = cnt;
    for (int u = t >> 3; u < nk; u += 32) {   // stage stop rows: 8 threads/row
        int l8 = (t & 7) * 8;
        f32x4 a = *(const f32x4*)&emb[kl[u] * D_EMB + l8];
        f32x4 b = *(const f32x4*)&emb[kl[u] * D_EMB + l8 + 4];
        *(f32x4*)&se[u][l8] = a;
        *(f32x4*)&se[u][l8 + 4] = b;
    }
    if (t < 8) {
        float s = 0.f;
        #pragma unroll
        for (int d = 0; d < D_EMB; ++d) s += xiS[t][d] * xiS[t][d];
        niS[t] = fmaxf(sqrtf(s), 1e-8f);
    }
    __syncthreads();
    for (int u = t; u < nk; u += 256) {
        float s = 0.f;
        #pragma unroll
        for (int d = 0; d < 16; ++d) {
            f32x4 v = *(const f32x4*)&se[u][d * 4];
            s += v[0] * v[0] + v[1] * v[1] + v[2] * v[2] + v[3] * v[3];
        }
        nrm[u] = fmaxf(sqrtf(s), 1e-8f);
    }
    __syncthreads();
    for (int u = t; u < nk; u += 256) {
        int j = kl[u];
        float nj = nrm[u];
        f32x4 er[16];
        #pragma unroll
        for (int d = 0; d < 16; ++d) er[d] = *(const f32x4*)&se[u][d * 4];
        #pragma unroll
        for (int n = 0; n < 8; ++n) {
            if (!kiS[n] || j == i0 + n) continue;
            f32x4 dv = {0.f, 0.f, 0.f, 0.f};
            #pragma unroll
            for (int d = 0; d < 16; ++d) dv += (*(const f32x4*)&xiS[n][d * 4]) * er[d];
            float dot = dv[0] + dv[1] + dv[2] + dv[3];
            if (dot > 0.5f * niS[n] * nj) {
                atomicAdd(&degS[n], 1);
                #pragma unroll
                for (int d = 0; d < 16; ++d) {
                    atomicAdd(&aggS[n][d * 4 + 0], er[d][0]);
                    atomicAdd(&aggS[n][d * 4 + 1], er[d][1]);
                    atomicAdd(&aggS[n][d * 4 + 2], er[d][2]);
                    atomicAdd(&aggS[n][d * 4 + 3], er[d][3]);
                }
            }
        }
    }
    __syncthreads();
    {   // finish: n = t>>5 node, p = t&31 pref dim
        int n = t >> 5, p = t & 31;
        int i = i0 + n;
        float inv = kiS[n] ? (1.f / fmaxf((float)degS[n], 1.0f)) : 0.f;
        float s = lin_l_b[p];
        const float* wl = &lin_l_w[p * D_EMB];
        const float* wr = &lin_r_w[p * D_EMB];
        #pragma unroll
        for (int d = 0; d < D_EMB; ++d) s += aggS[n][d] * inv * wl[d] + xiS[n][d] * wr[d];
        pref[i * P_DIM + p] = s;
        float a = s * edge_w[p];
        float b = s * edge_w[P_DIM + p];
        #pragma unroll
        for (int off = 16; off; off >>= 1) { a += __shfl_xor(a, off, 32); b += __shfl_xor(b, off, 32); }
        if (p == 0) { av[i] = a; bv[i] = b; keepf[i] = (float)kiS[n]; }
    }
}

// ---------------- tile-centric pack ----------------
// B: Bp[nt][kt][r(128)][c^(r&7)] (LDS-staged in gemm).
// A: per-lane FRAGMENT layout for direct global->VGPR loads in gemm:
//    within the 4096-u16 (rt,kt) block: idx = (grp*64 + quad*16 + l16)*8 + e
//    where row = rt*64 + (grp>>1)*16... precisely: grp = (row>>4 within strip)*2 + (kchunk>>2),
//    quad = kchunk&3, l16 = row&15.  gemm lane (quad*16+l16) loads 16 B at grp*512+lane*8.
__global__ __launch_bounds__(256) void k_pack(const float* __restrict__ comb_w, const float* __restrict__ comb_b,
                                              const int* __restrict__ wk_p, const int* __restrict__ vh_p,
                                              const float* __restrict__ dist, const float* __restrict__ pref,
                                              const float* __restrict__ av, const float* __restrict__ bv,
                                              const float* __restrict__ edge_b,
                                              u16* __restrict__ Bp, u16* __restrict__ Ap,
                                              float* __restrict__ cvec, float* __restrict__ w3) {
    int kt = blockIdx.x;       // 0..64
    int ty = blockIdx.y;       // 0..47
    int t = threadIdx.x;
    if (ty < 16) {             // ---- B tile: 128 rows x 64 cols = 1024 chunks of 16B ----
        int nt = ty;
        u16* tb = Bp + ((size_t)nt * NKT + kt) * 8192;
        #pragma unroll
        for (int it = 0; it < 4; ++it) {
            int q = t + it * 256;
            int r = q >> 3, c = q & 7;
            int j = nt * 128 + r;
            int k0 = kt * 64 + c * 8;
            const float* cw = comb_w + (size_t)j * IN_LEN;
            bf16x8 v;
            if (k0 < 4096) {
                f32x4 f0, f1;
                __builtin_memcpy(&f0, cw + 32 + k0, 16);
                __builtin_memcpy(&f1, cw + 36 + k0, 16);
                #pragma unroll
                for (int e = 0; e < 4; ++e) { v[e] = (short)f2bf(f0[e]); v[4 + e] = (short)f2bf(f1[e]); }
            } else if (k0 < 4128) {
                f32x4 f0, f1;
                __builtin_memcpy(&f0, cw + (k0 - 4096), 16);
                __builtin_memcpy(&f1, cw + (k0 - 4092), 16);
                #pragma unroll
                for (int e = 0; e < 4; ++e) { v[e] = (short)f2bf(f0[e]); v[4 + e] = (short)f2bf(f1[e]); }
            } else {
                #pragma unroll
                for (int e = 0; e < 8; ++e) v[e] = 0;
            }
            *(bf16x8*)&tb[r * 64 + ((c ^ (r & 7)) * 8)] = v;
        }
        if (kt == 64 && t < 128) {   // cvec/w3 once per row, done by the pad-kt blocks
            int j = nt * 128 + t;
            const float* cw = comb_w + (size_t)j * IN_LEN;
            float wk = (float)wk_p[0], vh = (float)vh_p[0];
            cvec[j] = wk * cw[4128] + vh * cw[4129] + comb_b[j];
            w3[j] = cw[4130];
        }
    } else {                   // ---- A tile: 64 rows x 64 cols, fragment layout ----
        int rt = ty - 16;
        u16* ta = Ap + ((size_t)rt * NKT + kt) * 4096;
        float eb = edge_b[0];
        #pragma unroll
        for (int it = 0; it < 2; ++it) {
            int q = t + it * 256;
            int r = q >> 3, kc = q & 7;          // source-coalesced: row r, kchunk kc
            int row = rt * 64 + r;
            int k0 = kt * 64 + kc * 8;
            bf16x8 v;
            if (k0 < 2048) {                 // es region: computed from av+bv
                float ab = av[row] + eb;
                f32x4 f0 = *(const f32x4*)(bv + k0);
                f32x4 f1 = *(const f32x4*)(bv + k0 + 4);
                #pragma unroll
                for (int e = 0; e < 4; ++e) {
                    float s0 = ab + f0[e]; s0 = (s0 >= 0.f) ? s0 : 0.01f * s0;
                    float s1 = ab + f1[e]; s1 = (s1 >= 0.f) ? s1 : 0.01f * s1;
                    v[e] = (short)f2bf(s0); v[4 + e] = (short)f2bf(s1);
                }
            } else if (k0 < 4096) {
                const f32x4* dp = (const f32x4*)(dist + (size_t)row * 2048 + (k0 - 2048));
                f32x4 f0 = dp[0], f1 = dp[1];
                #pragma unroll
                for (int e = 0; e < 4; ++e) { v[e] = (short)f2bf(f0[e]); v[4 + e] = (short)f2bf(f1[e]); }
            } else if (k0 < 4128) {
                const f32x4* pp = (const f32x4*)(pref + (size_t)row * P_DIM + (k0 - 4096));
                f32x4 f0 = pp[0], f1 = pp[1];
                #pragma unroll
                for (int e = 0; e < 4; ++e) { v[e] = (short)f2bf(f0[e]); v[4 + e] = (short)f2bf(f1[e]); }
            } else {
                #pragma unroll
                for (int e = 0; e < 8; ++e) v[e] = 0;
            }
            // fragment-layout destination: grp = (r>>4)*2 + (kc>>2), quad = kc&3, l16 = r&15
            int dst = ((((r >> 4) * 2 + (kc >> 2)) * 64) + (kc & 3) * 16 + (r & 15)) * 8;
            *(bf16x8*)&ta[dst] = v;
        }
    }
}

// ---------------- 64x64-tile GEMM: A direct global->VGPR (prefetched), B LDS-staged ----------------
// LDS-port traffic halved vs r7: per CU/kt = B-writes 32 KB + 64 ds_read_b128 (~1024 cyc vs ~2050).
// A fragments re-read 2x by waveN pairs -> L1 hits. 16 KB LDS/block, 4 blocks/CU, XCD chunking.
// Fused epilogue: C += cvec[col] + keepf[row]*w3[col].
__global__ __launch_bounds__(256, 4) void k_gemm_d(const u16* __restrict__ Ap, const u16* __restrict__ Bp,
                                                   const float* __restrict__ cvec, const float* __restrict__ w3,
                                                   const float* __restrict__ keepf,
                                                   float* __restrict__ Cout) {
    __shared__ __attribute__((aligned(16))) short Bs[2][4096];   // 2 x 8 KB
    int t = threadIdx.x;
    // bijective XCD-chunk decode: xcd = bid&7 (round-robin), chunk = 16mt x 8nt
    int b = blockIdx.x;                 // 0..1023
    int c = b & 7, u = b >> 3;          // chunk id, index within chunk
    int mt = (c & 1) * 16 + (u & 15);   // 0..31
    int nt = (c >> 1) * 8 + (u >> 4);   // 0..31
    int tileM = mt * 64, tileN = nt * 64;
    int lane = t & 63;
    int wid = t >> 6;                   // 0..3
    int waveM = wid & 1, waveN = wid >> 1;
    int l16 = lane & 15, quad = lane >> 4;

    f32x4 acc[2][2];
    #pragma unroll
    for (int a_ = 0; a_ < 2; ++a_)
        #pragma unroll
        for (int b_ = 0; b_ < 2; ++b_) acc[a_][b_] = (f32x4){0.f, 0.f, 0.f, 0.f};

    // A: per-lane fragment base; frag (mi,cb) at + kt*4096 + ((waveM*2+mi)*2+cb)*512
    const u16* gA = Ap + ((size_t)mt * NKT) * 4096 + lane * 8;
    const u16* gB = Bp + ((size_t)(nt >> 1) * NKT) * 8192 + (nt & 1) * 4096 + t * 8;

#define ISSUEB(ktv, bb) do { \
        const u16* b0 = gB + (size_t)(ktv) * 8192; \
        u16* bd = (u16*)Bs[bb] + t * 8; \
        gload16(b0, bd); \
        gload16(b0 + 2048, bd + 2048); \
    } while (0)

    ISSUEB(0, 0);
    bf16x8 a_cur[2][2];
    #pragma unroll
    for (int mi = 0; mi < 2; ++mi)
        #pragma unroll
        for (int cb = 0; cb < 2; ++cb)
            a_cur[mi][cb] = *(const bf16x8*)&gA[((waveM * 2 + mi) * 2 + cb) * 512];

    int cur = 0;
    for (int kt = 0; kt < NKT; ++kt) {
        bf16x8 a_nxt[2][2];
        __syncthreads();   // drains this tile's B DMA (issued a full MFMA phase ago, except kt=0)
        if (kt + 1 < NKT) {
            ISSUEB(kt + 1, cur ^ 1);
            const u16* gAn = gA + (size_t)(kt + 1) * 4096;
            #pragma unroll
            for (int mi = 0; mi < 2; ++mi)
                #pragma unroll
                for (int cb = 0; cb < 2; ++cb)
                    a_nxt[mi][cb] = *(const bf16x8*)&gAn[((waveM * 2 + mi) * 2 + cb) * 512];
        }
        const short* Bsc = Bs[cur];
        #pragma unroll
        for (int kk = 0; kk < 64; kk += 32) {
            int cbase = kk >> 3;       // 0 or 4
            int cb = kk >> 5;          // 0 or 1
            bf16x8 bfr[2];
            #pragma unroll
            for (int ni = 0; ni < 2; ++ni) {
                int row = waveN * 32 + ni * 16 + l16;
                bfr[ni] = *(const bf16x8*)&Bsc[SWZ(row, cbase + quad)];
            }
            #pragma unroll
            for (int mi = 0; mi < 2; ++mi)
                #pragma unroll
                for (int ni = 0; ni < 2; ++ni)
                    acc[mi][ni] = __builtin_amdgcn_mfma_f32_16x16x32_bf16(
                        cb ? a_cur[mi][1] : a_cur[mi][0], bfr[ni], acc[mi][ni], 0, 0, 0);
        }
        #pragma unroll
        for (int mi = 0; mi < 2; ++mi)
            #pragma unroll
            for (int cb = 0; cb < 2; ++cb)
                a_cur[mi][cb] = a_nxt[mi][cb];
        cur ^= 1;
    }
#undef ISSUEB
    #pragma unroll
    for (int mi = 0; mi < 2; ++mi)
        #pragma unroll
        for (int ni = 0; ni < 2; ++ni) {
            int row0 = tileM + waveM * 32 + mi * 16 + quad * 4;
            int col = tileN + waveN * 32 + ni * 16 + l16;
            float cv = cvec[col], wv = w3[col];
            float* cp = Cout + (size_t)row0 * N_NODES + col;
            #pragma unroll
            for (int rr = 0; rr < 4; ++rr)
                cp[(size_t)rr * N_NODES] = acc[mi][ni][rr] + cv + keepf[row0 + rr] * wv;
        }
}

// ---------------- epilogue: pure in-place log-softmax (adds fused into GEMM) ----------------
__global__ __launch_bounds__(256) void k_epi(float* __restrict__ out) {
    int i = blockIdx.x, t = threadIdx.x;
    __shared__ float redmax[4], redsum[4];
    f32x4* orow = (f32x4*)(out + (size_t)i * N_NODES);
    f32x4 v0 = orow[t];
    f32x4 v1 = orow[t + 256];
    float vmax = fmaxf(fmaxf(fmaxf(v0[0], v0[1]), fmaxf(v0[2], v0[3])),
                       fmaxf(fmaxf(v1[0], v1[1]), fmaxf(v1[2], v1[3])));
    #pragma unroll
    for (int off = 32; off; off >>= 1) vmax = fmaxf(vmax, __shfl_xor(vmax, off, 64));
    if ((t & 63) == 0) redmax[t >> 6] = vmax;
    __syncthreads();
    vmax = fmaxf(fmaxf(redmax[0], redmax[1]), fmaxf(redmax[2], redmax[3]));
    float se = 0.f;
    #pragma unroll
    for (int e = 0; e < 4; ++e) se += expf(v0[e] - vmax) + expf(v1[e] - vmax);
    #pragma unroll
    for (int off = 32; off; off >>= 1) se += __shfl_xor(se, off, 64);
    if ((t & 63) == 0) redsum[t >> 6] = se;
    __syncthreads();
    se = redsum[0] + redsum[1] + redsum[2] + redsum[3];
    float lz = vmax + logf(se);
    orow[t] = v0 - lz;
    orow[t + 256] = v1 - lz;
}

extern "C" void kernel_launch(void* const* d_in, const int* in_sizes, int n_in,
                              void* d_out, int out_size, void* d_ws, size_t ws_size,
                              hipStream_t stream) {
    const float* dist    = (const float*)d_in[0];
    const float* emb     = (const float*)d_in[1];
    const float* lin_l_w = (const float*)d_in[2];
    const float* lin_l_b = (const float*)d_in[3];
    const float* lin_r_w = (const float*)d_in[4];
    const float* edge_w  = (const float*)d_in[5];
    const float* edge_b  = (const float*)d_in[6];
    const float* comb_w  = (const float*)d_in[7];
    const float* comb_b  = (const float*)d_in[8];
    const int* stops     = (const int*)d_in[9];
    const int* wk        = (const int*)d_in[10];
    const int* vh        = (const int*)d_in[11];

    // ws layout: 34.4 MB (budget >= 35.43 MB)
    char* ws = (char*)d_ws;
    float* pref  = (float*)(ws + 0);          // 262144
    float* av    = (float*)(ws + 262144);     // 8192
    float* bv    = (float*)(ws + 270336);     // 8192
    float* cvec  = (float*)(ws + 278528);     // 8192
    float* w3    = (float*)(ws + 286720);     // 8192
    float* keepf = (float*)(ws + 294912);     // 8192
    u16*   Ap    = (u16*)(ws + 303104);       // 17039360 -> 17342464
    u16*   Bp    = (u16*)(ws + 17342464);     // 17039360 -> 34381824
    float* out   = (float*)d_out;             // f32 [2048,2048]

    hipLaunchKernelGGL(k_aggpref, dim3(256),    dim3(256), 0, stream, emb, stops,
                       lin_l_w, lin_l_b, lin_r_w, edge_w, pref, av, bv, keepf);
    hipLaunchKernelGGL(k_pack,    dim3(65, 48), dim3(256), 0, stream, comb_w, comb_b, wk, vh,
                       dist, pref, av, bv, edge_b, Bp, Ap, cvec, w3);
    hipLaunchKernelGGL(k_gemm_d,  dim3(1024),   dim3(256), 0, stream, Ap, Bp, cvec, w3, keepf, out);
    hipLaunchKernelGGL(k_epi,     dim3(2048),   dim3(256), 0, stream, out);
}

// Round 9
// 191.381 us; speedup vs baseline: 1.0383x; 1.0383x over previous
//
#include <hip/hip_runtime.h>

typedef unsigned short u16;
typedef __attribute__((ext_vector_type(8))) short bf16x8;
typedef __attribute__((ext_vector_type(4))) float f32x4;

// round-to-nearest (ties away): 2 VALU ops
__device__ __forceinline__ u16 f2bf(float f) {
    return (u16)((__float_as_uint(f) + 0x8000u) >> 16);
}

#define N_NODES 2048
#define D_EMB 64
#define P_DIM 32
#define NS_STOPS 512
#define IN_LEN 4131   // 32 + 2048 + 2048 + 3
#define NKTP 66       // K-tiles of 64, padded to even (2048 es + 2048 dist + 32 pref + 32 pad + 64 zero)
#define NPH 33        // phases of BK=128 (2 kt each)

// 16B-chunk XOR swizzle within a tile row (8 chunks of 8 shorts)
#define SWZ(row, c) ((((row) * 8) + ((c) ^ ((row) & 7))) * 8)

__device__ __forceinline__ void gload16(const u16* g, u16* l) {
    __builtin_amdgcn_global_load_lds((const __attribute__((address_space(1))) void*)g,
                                     (__attribute__((address_space(3))) void*)l, 16, 0, 0);
}

// ---------------- LDS-staged aggpref: 256 blocks x 8 nodes; stop rows staged ONCE ----------------
__global__ __launch_bounds__(256) void k_aggpref(const float* __restrict__ emb, const int* __restrict__ stops,
                                                 const float* __restrict__ lin_l_w, const float* __restrict__ lin_l_b,
                                                 const float* __restrict__ lin_r_w, const float* __restrict__ edge_w,
                                                 float* __restrict__ pref, float* __restrict__ av, float* __restrict__ bv,
                                                 float* __restrict__ keepf) {
    __shared__ float se[NS_STOPS][68];   // 139264 B; 17-word row stride -> conflict-free
    __shared__ int bm[64];
    __shared__ int kl[NS_STOPS];
    __shared__ float nrm[NS_STOPS];
    __shared__ float xiS[8][D_EMB];
    __shared__ float aggS[8][D_EMB];
    __shared__ float niS[8];
    __shared__ int degS[8];
    __shared__ int kiS[8];
    __shared__ int cnt;
    int t = threadIdx.x;
    int i0 = blockIdx.x * 8;
    if (t < 64) bm[t] = 0;
    if (t == 0) cnt = 0;
    if (t < 8) degS[t] = 0;
    ((float*)aggS)[t] = 0.f;
    ((float*)aggS)[t + 256] = 0.f;
    __syncthreads();
    {   // scatter stops into bitmap
        int s0 = stops[t], s1 = stops[t + 256];
        atomicOr(&bm[s0 >> 5], 1 << (s0 & 31));
        atomicOr(&bm[s1 >> 5], 1 << (s1 & 31));
    }
    __syncthreads();
    {   // compact set nodes into kl
        int w = bm[t >> 2];
        int base = (t >> 2) * 32 + (t & 3) * 8;
        #pragma unroll
        for (int e = 0; e < 8; ++e)
            if ((w >> ((t & 3) * 8 + e)) & 1) { int p = atomicAdd(&cnt, 1); kl[p] = base + e; }
    }
    if (t < 8) { int i = i0 + t; kiS[t] = (bm[i >> 5] >> (i & 31)) & 1; }
    {   // load this block's 8 node rows
        int n = t >> 5, d = (t & 31) * 2;
        xiS[n][d]     = emb[(i0 + n) * D_EMB + d];
        xiS[n][d + 1] = emb[(i0 + n) * D_EMB + d + 1];
    }
    __syncthreads();
    int nk = cnt;
    for (int u = t >> 3; u < nk; u += 32) {   // stage stop rows: 8 threads/row
        int l8 = (t & 7) * 8;
        f32x4 a = *(const f32x4*)&emb[kl[u] * D_EMB + l8];
        f32x4 b = *(const f32x4*)&emb[kl[u] * D_EMB + l8 + 4];
        *(f32x4*)&se[u][l8] = a;
        *(f32x4*)&se[u][l8 + 4] = b;
    }
    if (t < 8) {
        float s = 0.f;
        #pragma unroll
        for (int d = 0; d < D_EMB; ++d) s += xiS[t][d] * xiS[t][d];
        niS[t] = fmaxf(sqrtf(s), 1e-8f);
    }
    __syncthreads();
    for (int u = t; u < nk; u += 256) {
        float s = 0.f;
        #pragma unroll
        for (int d = 0; d < 16; ++d) {
            f32x4 v = *(const f32x4*)&se[u][d * 4];
            s += v[0] * v[0] + v[1] * v[1] + v[2] * v[2] + v[3] * v[3];
        }
        nrm[u] = fmaxf(sqrtf(s), 1e-8f);
    }
    __syncthreads();
    for (int u = t; u < nk; u += 256) {
        int j = kl[u];
        float nj = nrm[u];
        f32x4 er[16];
        #pragma unroll
        for (int d = 0; d < 16; ++d) er[d] = *(const f32x4*)&se[u][d * 4];
        #pragma unroll
        for (int n = 0; n < 8; ++n) {
            if (!kiS[n] || j == i0 + n) continue;
            f32x4 dv = {0.f, 0.f, 0.f, 0.f};
            #pragma unroll
            for (int d = 0; d < 16; ++d) dv += (*(const f32x4*)&xiS[n][d * 4]) * er[d];
            float dot = dv[0] + dv[1] + dv[2] + dv[3];
            if (dot > 0.5f * niS[n] * nj) {
                atomicAdd(&degS[n], 1);
                #pragma unroll
                for (int d = 0; d < 16; ++d) {
                    atomicAdd(&aggS[n][d * 4 + 0], er[d][0]);
                    atomicAdd(&aggS[n][d * 4 + 1], er[d][1]);
                    atomicAdd(&aggS[n][d * 4 + 2], er[d][2]);
                    atomicAdd(&aggS[n][d * 4 + 3], er[d][3]);
                }
            }
        }
    }
    __syncthreads();
    {   // finish: n = t>>5 node, p = t&31 pref dim
        int n = t >> 5, p = t & 31;
        int i = i0 + n;
        float inv = kiS[n] ? (1.f / fmaxf((float)degS[n], 1.0f)) : 0.f;
        float s = lin_l_b[p];
        const float* wl = &lin_l_w[p * D_EMB];
        const float* wr = &lin_r_w[p * D_EMB];
        #pragma unroll
        for (int d = 0; d < D_EMB; ++d) s += aggS[n][d] * inv * wl[d] + xiS[n][d] * wr[d];
        pref[i * P_DIM + p] = s;
        float a = s * edge_w[p];
        float b = s * edge_w[P_DIM + p];
        #pragma unroll
        for (int off = 16; off; off >>= 1) { a += __shfl_xor(a, off, 32); b += __shfl_xor(b, off, 32); }
        if (p == 0) { av[i] = a; bv[i] = b; keepf[i] = (float)kiS[n]; }
    }
}

// ---------------- tile-centric pack: each block owns one contiguous (tile, kt) region ----------------
// grid = dim3(66, 48): blockIdx.x = kt (kt=65 -> zero pad); ty < 16 -> B tile nt ; >= 16 -> A tile rt
// Bp[nt][kt(66)][r(128)][c^(r&7)] ; Ap[rt(32)][kt(66)][r(64)][c^(r&7)]
__global__ __launch_bounds__(256) void k_pack(const float* __restrict__ comb_w, const float* __restrict__ comb_b,
                                              const int* __restrict__ wk_p, const int* __restrict__ vh_p,
                                              const float* __restrict__ dist, const float* __restrict__ pref,
                                              const float* __restrict__ av, const float* __restrict__ bv,
                                              const float* __restrict__ edge_b,
                                              u16* __restrict__ Bp, u16* __restrict__ Ap,
                                              float* __restrict__ cvec, float* __restrict__ w3) {
    int kt = blockIdx.x;       // 0..65
    int ty = blockIdx.y;       // 0..47
    int t = threadIdx.x;
    if (ty < 16) {             // ---- B tile: 128 rows x 64 cols = 1024 chunks of 16B ----
        int nt = ty;
        u16* tb = Bp + ((size_t)nt * NKTP + kt) * 8192;
        #pragma unroll
        for (int it = 0; it < 4; ++it) {
            int q = t + it * 256;
            int r = q >> 3, c = q & 7;
            int j = nt * 128 + r;
            int k0 = kt * 64 + c * 8;
            const float* cw = comb_w + (size_t)j * IN_LEN;
            bf16x8 v;
            if (k0 < 4096) {
                f32x4 f0, f1;
                __builtin_memcpy(&f0, cw + 32 + k0, 16);
                __builtin_memcpy(&f1, cw + 36 + k0, 16);
                #pragma unroll
                for (int e = 0; e < 4; ++e) { v[e] = (short)f2bf(f0[e]); v[4 + e] = (short)f2bf(f1[e]); }
            } else if (k0 < 4128) {
                f32x4 f0, f1;
                __builtin_memcpy(&f0, cw + (k0 - 4096), 16);
                __builtin_memcpy(&f1, cw + (k0 - 4092), 16);
                #pragma unroll
                for (int e = 0; e < 4; ++e) { v[e] = (short)f2bf(f0[e]); v[4 + e] = (short)f2bf(f1[e]); }
            } else {
                #pragma unroll
                for (int e = 0; e < 8; ++e) v[e] = 0;
            }
            *(bf16x8*)&tb[r * 64 + ((c ^ (r & 7)) * 8)] = v;
        }
        if (kt == 64 && t < 128) {   // cvec/w3 once per row
            int j = nt * 128 + t;
            const float* cw = comb_w + (size_t)j * IN_LEN;
            float wk = (float)wk_p[0], vh = (float)vh_p[0];
            cvec[j] = wk * cw[4128] + vh * cw[4129] + comb_b[j];
            w3[j] = cw[4130];
        }
    } else {                   // ---- A tile: 64 rows x 64 cols = 512 chunks of 16B ----
        int rt = ty - 16;
        u16* ta = Ap + ((size_t)rt * NKTP + kt) * 4096;
        float eb = edge_b[0];
        #pragma unroll
        for (int it = 0; it < 2; ++it) {
            int q = t + it * 256;
            int r = q >> 3, c = q & 7;
            int row = rt * 64 + r;
            int k0 = kt * 64 + c * 8;
            bf16x8 v;
            if (k0 < 2048) {                 // es region: computed from av+bv
                float ab = av[row] + eb;
                f32x4 f0 = *(const f32x4*)(bv + k0);
                f32x4 f1 = *(const f32x4*)(bv + k0 + 4);
                #pragma unroll
                for (int e = 0; e < 4; ++e) {
                    float s0 = ab + f0[e]; s0 = (s0 >= 0.f) ? s0 : 0.01f * s0;
                    float s1 = ab + f1[e]; s1 = (s1 >= 0.f) ? s1 : 0.01f * s1;
                    v[e] = (short)f2bf(s0); v[4 + e] = (short)f2bf(s1);
                }
            } else if (k0 < 4096) {
                const f32x4* dp = (const f32x4*)(dist + (size_t)row * 2048 + (k0 - 2048));
                f32x4 f0 = dp[0], f1 = dp[1];
                #pragma unroll
                for (int e = 0; e < 4; ++e) { v[e] = (short)f2bf(f0[e]); v[4 + e] = (short)f2bf(f1[e]); }
            } else if (k0 < 4128) {
                const f32x4* pp = (const f32x4*)(pref + (size_t)row * P_DIM + (k0 - 4096));
                f32x4 f0 = pp[0], f1 = pp[1];
                #pragma unroll
                for (int e = 0; e < 4; ++e) { v[e] = (short)f2bf(f0[e]); v[4 + e] = (short)f2bf(f1[e]); }
            } else {
                #pragma unroll
                for (int e = 0; e < 8; ++e) v[e] = 0;
            }
            *(bf16x8*)&ta[r * 64 + ((c ^ (r & 7)) * 8)] = v;
        }
    }
}

// ---------------- 64x64-tile DMA GEMM, BK=128: 2 kt per barrier (33 phases vs 65) ----------------
// Theory: per-phase stage->drain->barrier overhead is ~constant (m233); halving phase count
// amortizes it over 2x MFMA. 64 KB LDS -> 2 blocks/CU (8 waves). XCD chunking kept.
// Fused epilogue: C += cvec[col] + keepf[row]*w3[col].
__global__ __launch_bounds__(256, 2) void k_gemm_d(const u16* __restrict__ Ap, const u16* __restrict__ Bp,
                                                   const float* __restrict__ cvec, const float* __restrict__ w3,
                                                   const float* __restrict__ keepf,
                                                   float* __restrict__ Cout) {
    __shared__ __attribute__((aligned(16))) short As[2][8192];   // 2 x 16 KB (two 4096-u16 kt sub-tiles)
    __shared__ __attribute__((aligned(16))) short Bs[2][8192];   // 2 x 16 KB
    int t = threadIdx.x;
    // bijective XCD-chunk decode: xcd = bid&7 (round-robin), chunk = 16mt x 8nt
    int b = blockIdx.x;                 // 0..1023
    int c = b & 7, u = b >> 3;          // chunk id, index within chunk
    int mt = (c & 1) * 16 + (u & 15);   // 0..31
    int nt = (c >> 1) * 8 + (u >> 4);   // 0..31
    int tileM = mt * 64, tileN = nt * 64;
    int lane = t & 63;
    int wid = t >> 6;                   // 0..3
    int waveM = wid & 1, waveN = wid >> 1;
    int l16 = lane & 15, quad = lane >> 4;

    f32x4 acc[2][2];
    #pragma unroll
    for (int a_ = 0; a_ < 2; ++a_)
        #pragma unroll
        for (int b_ = 0; b_ < 2; ++b_) acc[a_][b_] = (f32x4){0.f, 0.f, 0.f, 0.f};

    // A: strip mt (64 rows), 4096 u16 per kt.  B: 64-row half of 128-row strip nt>>1.
    const u16* gA = Ap + ((size_t)mt * NKTP) * 4096 + t * 8;
    const u16* gB = Bp + ((size_t)(nt >> 1) * NKTP) * 8192 + (nt & 1) * 4096 + t * 8;

#define ISSUE2(ph, bb) do { \
        const u16* a0 = gA + (size_t)(2 * (ph)) * 4096; \
        const u16* b0 = gB + (size_t)(2 * (ph)) * 8192; \
        u16* ad = (u16*)As[bb] + t * 8; \
        u16* bd = (u16*)Bs[bb] + t * 8; \
        gload16(a0, ad); \
        gload16(a0 + 2048, ad + 2048); \
        gload16(a0 + 4096, ad + 4096); \
        gload16(a0 + 6144, ad + 6144); \
        gload16(b0, bd); \
        gload16(b0 + 2048, bd + 2048); \
        gload16(b0 + 8192, bd + 4096); \
        gload16(b0 + 10240, bd + 6144); \
    } while (0)

    ISSUE2(0, 0);   // preload phase 0 (kt 0,1) into buffer 0

    int cur = 0;
    for (int ph = 0; ph < NPH; ++ph) {
        __syncthreads();   // drains this phase's DMA (issued a full MFMA phase ago, except ph=0)
        if (ph + 1 < NPH) ISSUE2(ph + 1, cur ^ 1);
        #pragma unroll
        for (int sub = 0; sub < 2; ++sub) {
            const short* Asc = As[cur] + sub * 4096;
            const short* Bsc = Bs[cur] + sub * 4096;
            #pragma unroll
            for (int kk = 0; kk < 64; kk += 32) {
                int cbase = kk >> 3;
                bf16x8 af[2], bfr[2];
                #pragma unroll
                for (int mi = 0; mi < 2; ++mi) {
                    int row = waveM * 32 + mi * 16 + l16;
                    af[mi] = *(const bf16x8*)&Asc[SWZ(row, cbase + quad)];
                }
                #pragma unroll
                for (int ni = 0; ni < 2; ++ni) {
                    int row = waveN * 32 + ni * 16 + l16;
                    bfr[ni] = *(const bf16x8*)&Bsc[SWZ(row, cbase + quad)];
                }
                #pragma unroll
                for (int mi = 0; mi < 2; ++mi)
                    #pragma unroll
                    for (int ni = 0; ni < 2; ++ni)
                        acc[mi][ni] = __builtin_amdgcn_mfma_f32_16x16x32_bf16(af[mi], bfr[ni], acc[mi][ni], 0, 0, 0);
            }
        }
        cur ^= 1;
    }
#undef ISSUE2
    #pragma unroll
    for (int mi = 0; mi < 2; ++mi)
        #pragma unroll
        for (int ni = 0; ni < 2; ++ni) {
            int row0 = tileM + waveM * 32 + mi * 16 + quad * 4;
            int col = tileN + waveN * 32 + ni * 16 + l16;
            float cv = cvec[col], wv = w3[col];
            float* cp = Cout + (size_t)row0 * N_NODES + col;
            #pragma unroll
            for (int rr = 0; rr < 4; ++rr)
                cp[(size_t)rr * N_NODES] = acc[mi][ni][rr] + cv + keepf[row0 + rr] * wv;
        }
}

// ---------------- epilogue: pure in-place log-softmax (adds fused into GEMM) ----------------
__global__ __launch_bounds__(256) void k_epi(float* __restrict__ out) {
    int i = blockIdx.x, t = threadIdx.x;
    __shared__ float redmax[4], redsum[4];
    f32x4* orow = (f32x4*)(out + (size_t)i * N_NODES);
    f32x4 v0 = orow[t];
    f32x4 v1 = orow[t + 256];
    float vmax = fmaxf(fmaxf(fmaxf(v0[0], v0[1]), fmaxf(v0[2], v0[3])),
                       fmaxf(fmaxf(v1[0], v1[1]), fmaxf(v1[2], v1[3])));
    #pragma unroll
    for (int off = 32; off; off >>= 1) vmax = fmaxf(vmax, __shfl_xor(vmax, off, 64));
    if ((t & 63) == 0) redmax[t >> 6] = vmax;
    __syncthreads();
    vmax = fmaxf(fmaxf(redmax[0], redmax[1]), fmaxf(redmax[2], redmax[3]));
    float se = 0.f;
    #pragma unroll
    for (int e = 0; e < 4; ++e) se += expf(v0[e] - vmax) + expf(v1[e] - vmax);
    #pragma unroll
    for (int off = 32; off; off >>= 1) se += __shfl_xor(se, off, 64);
    if ((t & 63) == 0) redsum[t >> 6] = se;
    __syncthreads();
    se = redsum[0] + redsum[1] + redsum[2] + redsum[3];
    float lz = vmax + logf(se);
    orow[t] = v0 - lz;
    orow[t + 256] = v1 - lz;
}

extern "C" void kernel_launch(void* const* d_in, const int* in_sizes, int n_in,
                              void* d_out, int out_size, void* d_ws, size_t ws_size,
                              hipStream_t stream) {
    const float* dist    = (const float*)d_in[0];
    const float* emb     = (const float*)d_in[1];
    const float* lin_l_w = (const float*)d_in[2];
    const float* lin_l_b = (const float*)d_in[3];
    const float* lin_r_w = (const float*)d_in[4];
    const float* edge_w  = (const float*)d_in[5];
    const float* edge_b  = (const float*)d_in[6];
    const float* comb_w  = (const float*)d_in[7];
    const float* comb_b  = (const float*)d_in[8];
    const int* stops     = (const int*)d_in[9];
    const int* wk        = (const int*)d_in[10];
    const int* vh        = (const int*)d_in[11];

    // ws layout: 34.9 MB (budget >= 35.43 MB); Ap = 32*66*8KB = 16.5 MB, Bp = 16*66*16KB = 16.5 MB
    char* ws = (char*)d_ws;
    float* pref  = (float*)(ws + 0);          // 262144
    float* av    = (float*)(ws + 262144);     // 8192
    float* bv    = (float*)(ws + 270336);     // 8192
    float* cvec  = (float*)(ws + 278528);     // 8192
    float* w3    = (float*)(ws + 286720);     // 8192
    float* keepf = (float*)(ws + 294912);     // 8192
    u16*   Ap    = (u16*)(ws + 303104);       // 17301504 -> 17604608
    u16*   Bp    = (u16*)(ws + 17604608);     // 17301504 -> 34906112
    float* out   = (float*)d_out;             // f32 [2048,2048]

    hipLaunchKernelGGL(k_aggpref, dim3(256),    dim3(256), 0, stream, emb, stops,
                       lin_l_w, lin_l_b, lin_r_w, edge_w, pref, av, bv, keepf);
    hipLaunchKernelGGL(k_pack,    dim3(66, 48), dim3(256), 0, stream, comb_w, comb_b, wk, vh,
                       dist, pref, av, bv, edge_b, Bp, Ap, cvec, w3);
    hipLaunchKernelGGL(k_gemm_d,  dim3(1024),   dim3(256), 0, stream, Ap, Bp, cvec, w3, keepf, out);
    hipLaunchKernelGGL(k_epi,     dim3(2048),   dim3(256), 0, stream, out);
}

// Round 10
// 184.817 us; speedup vs baseline: 1.0752x; 1.0355x over previous
//
#include <hip/hip_runtime.h>

typedef unsigned short u16;
typedef __attribute__((ext_vector_type(8))) short bf16x8;
typedef __attribute__((ext_vector_type(4))) float f32x4;

// round-to-nearest (ties away): 2 VALU ops
__device__ __forceinline__ u16 f2bf(float f) {
    return (u16)((__float_as_uint(f) + 0x8000u) >> 16);
}

#define N_NODES 2048
#define D_EMB 64
#define P_DIM 32
#define NS_STOPS 512
#define IN_LEN 4131   // 32 + 2048 + 2048 + 3
#define NKT 65        // K-tiles of 64 (2048 es + 2048 dist + 32 pref + 32 pad)

// 16B-chunk XOR swizzle within a tile row (8 chunks of 8 shorts)
#define SWZ(row, c) ((((row) * 8) + ((c) ^ ((row) & 7))) * 8)

__device__ __forceinline__ void gload16(const u16* g, u16* l) {
    __builtin_amdgcn_global_load_lds((const __attribute__((address_space(1))) void*)g,
                                     (__attribute__((address_space(3))) void*)l, 16, 0, 0);
}

// ---------------- aggpref: 256 blocks x 8 nodes, UNSTAGED (emb is 512 KB -> L2-resident) ----------------
// Reads each stop row straight into registers (16 x f32x4, high ILP), norm inline; no big LDS
// buffer -> no 1-block/CU occupancy cap (was 139 KB staged).
__global__ __launch_bounds__(256) void k_aggpref(const float* __restrict__ emb, const int* __restrict__ stops,
                                                 const float* __restrict__ lin_l_w, const float* __restrict__ lin_l_b,
                                                 const float* __restrict__ lin_r_w, const float* __restrict__ edge_w,
                                                 float* __restrict__ pref, float* __restrict__ av, float* __restrict__ bv,
                                                 float* __restrict__ keepf) {
    __shared__ int bm[64];
    __shared__ int kl[NS_STOPS];
    __shared__ float xiS[8][D_EMB];
    __shared__ float aggS[8][D_EMB];
    __shared__ float niS[8];
    __shared__ int degS[8];
    __shared__ int kiS[8];
    __shared__ int cnt;
    int t = threadIdx.x;
    int i0 = blockIdx.x * 8;
    if (t < 64) bm[t] = 0;
    if (t == 0) cnt = 0;
    if (t < 8) degS[t] = 0;
    ((float*)aggS)[t] = 0.f;
    ((float*)aggS)[t + 256] = 0.f;
    __syncthreads();
    {   // scatter stops into bitmap
        int s0 = stops[t], s1 = stops[t + 256];
        atomicOr(&bm[s0 >> 5], 1 << (s0 & 31));
        atomicOr(&bm[s1 >> 5], 1 << (s1 & 31));
    }
    __syncthreads();
    {   // compact set nodes into kl
        int w = bm[t >> 2];
        int base = (t >> 2) * 32 + (t & 3) * 8;
        #pragma unroll
        for (int e = 0; e < 8; ++e)
            if ((w >> ((t & 3) * 8 + e)) & 1) { int p = atomicAdd(&cnt, 1); kl[p] = base + e; }
    }
    if (t < 8) { int i = i0 + t; kiS[t] = (bm[i >> 5] >> (i & 31)) & 1; }
    {   // load this block's 8 node rows
        int n = t >> 5, d = (t & 31) * 2;
        xiS[n][d]     = emb[(i0 + n) * D_EMB + d];
        xiS[n][d + 1] = emb[(i0 + n) * D_EMB + d + 1];
    }
    __syncthreads();
    if (t < 8) {
        float s = 0.f;
        #pragma unroll
        for (int d = 0; d < D_EMB; ++d) s += xiS[t][d] * xiS[t][d];
        niS[t] = fmaxf(sqrtf(s), 1e-8f);
    }
    __syncthreads();
    int nk = cnt;
    for (int u = t; u < nk; u += 256) {
        int j = kl[u];
        const f32x4* ej = (const f32x4*)&emb[j * D_EMB];
        f32x4 er[16];
        f32x4 sv = {0.f, 0.f, 0.f, 0.f};
        #pragma unroll
        for (int d = 0; d < 16; ++d) { er[d] = ej[d]; sv += er[d] * er[d]; }
        float nj = fmaxf(sqrtf(sv[0] + sv[1] + sv[2] + sv[3]), 1e-8f);
        #pragma unroll
        for (int n = 0; n < 8; ++n) {
            if (!kiS[n] || j == i0 + n) continue;
            f32x4 dv = {0.f, 0.f, 0.f, 0.f};
            #pragma unroll
            for (int d = 0; d < 16; ++d) dv += (*(const f32x4*)&xiS[n][d * 4]) * er[d];
            float dot = dv[0] + dv[1] + dv[2] + dv[3];
            if (dot > 0.5f * niS[n] * nj) {
                atomicAdd(&degS[n], 1);
                #pragma unroll
                for (int d = 0; d < 16; ++d) {
                    atomicAdd(&aggS[n][d * 4 + 0], er[d][0]);
                    atomicAdd(&aggS[n][d * 4 + 1], er[d][1]);
                    atomicAdd(&aggS[n][d * 4 + 2], er[d][2]);
                    atomicAdd(&aggS[n][d * 4 + 3], er[d][3]);
                }
            }
        }
    }
    __syncthreads();
    {   // finish: n = t>>5 node, p = t&31 pref dim
        int n = t >> 5, p = t & 31;
        int i = i0 + n;
        float inv = kiS[n] ? (1.f / fmaxf((float)degS[n], 1.0f)) : 0.f;
        float s = lin_l_b[p];
        const float* wl = &lin_l_w[p * D_EMB];
        const float* wr = &lin_r_w[p * D_EMB];
        #pragma unroll
        for (int d = 0; d < D_EMB; ++d) s += aggS[n][d] * inv * wl[d] + xiS[n][d] * wr[d];
        pref[i * P_DIM + p] = s;
        float a = s * edge_w[p];
        float b = s * edge_w[P_DIM + p];
        #pragma unroll
        for (int off = 16; off; off >>= 1) { a += __shfl_xor(a, off, 32); b += __shfl_xor(b, off, 32); }
        if (p == 0) { av[i] = a; bv[i] = b; keepf[i] = (float)kiS[n]; }
    }
}

// ---------------- tile-centric pack: each block owns one contiguous (tile, kt) region ----------------
// grid = dim3(65, 48): blockIdx.x = kt; blockIdx.y < 16 -> B tile nt ; >= 16 -> A tile rt = y-16
// Bp[nt][kt][r(128)][c^(r&7)] ; Ap[rt(32)][kt][r(64)][c^(r&7)]
__global__ __launch_bounds__(256) void k_pack(const float* __restrict__ comb_w, const float* __restrict__ comb_b,
                                              const int* __restrict__ wk_p, const int* __restrict__ vh_p,
                                              const float* __restrict__ dist, const float* __restrict__ pref,
                                              const float* __restrict__ av, const float* __restrict__ bv,
                                              const float* __restrict__ edge_b,
                                              u16* __restrict__ Bp, u16* __restrict__ Ap,
                                              float* __restrict__ cvec, float* __restrict__ w3) {
    int kt = blockIdx.x;       // 0..64
    int ty = blockIdx.y;       // 0..47
    int t = threadIdx.x;
    if (ty < 16) {             // ---- B tile: 128 rows x 64 cols = 1024 chunks of 16B ----
        int nt = ty;
        u16* tb = Bp + ((size_t)nt * NKT + kt) * 8192;
        #pragma unroll
        for (int it = 0; it < 4; ++it) {
            int q = t + it * 256;
            int r = q >> 3, c = q & 7;
            int j = nt * 128 + r;
            int k0 = kt * 64 + c * 8;
            const float* cw = comb_w + (size_t)j * IN_LEN;
            bf16x8 v;
            if (k0 < 4096) {
                f32x4 f0, f1;
                __builtin_memcpy(&f0, cw + 32 + k0, 16);
                __builtin_memcpy(&f1, cw + 36 + k0, 16);
                #pragma unroll
                for (int e = 0; e < 4; ++e) { v[e] = (short)f2bf(f0[e]); v[4 + e] = (short)f2bf(f1[e]); }
            } else if (k0 < 4128) {
                f32x4 f0, f1;
                __builtin_memcpy(&f0, cw + (k0 - 4096), 16);
                __builtin_memcpy(&f1, cw + (k0 - 4092), 16);
                #pragma unroll
                for (int e = 0; e < 4; ++e) { v[e] = (short)f2bf(f0[e]); v[4 + e] = (short)f2bf(f1[e]); }
            } else {
                #pragma unroll
                for (int e = 0; e < 8; ++e) v[e] = 0;
            }
            *(bf16x8*)&tb[r * 64 + ((c ^ (r & 7)) * 8)] = v;
        }
        if (kt == 64 && t < 128) {   // cvec/w3 once per row
            int j = nt * 128 + t;
            const float* cw = comb_w + (size_t)j * IN_LEN;
            float wk = (float)wk_p[0], vh = (float)vh_p[0];
            cvec[j] = wk * cw[4128] + vh * cw[4129] + comb_b[j];
            w3[j] = cw[4130];
        }
    } else {                   // ---- A tile: 64 rows x 64 cols = 512 chunks of 16B ----
        int rt = ty - 16;
        u16* ta = Ap + ((size_t)rt * NKT + kt) * 4096;
        float eb = edge_b[0];
        #pragma unroll
        for (int it = 0; it < 2; ++it) {
            int q = t + it * 256;
            int r = q >> 3, c = q & 7;
            int row = rt * 64 + r;
            int k0 = kt * 64 + c * 8;
            bf16x8 v;
            if (k0 < 2048) {                 // es region: computed from av+bv
                float ab = av[row] + eb;
                f32x4 f0 = *(const f32x4*)(bv + k0);
                f32x4 f1 = *(const f32x4*)(bv + k0 + 4);
                #pragma unroll
                for (int e = 0; e < 4; ++e) {
                    float s0 = ab + f0[e]; s0 = (s0 >= 0.f) ? s0 : 0.01f * s0;
                    float s1 = ab + f1[e]; s1 = (s1 >= 0.f) ? s1 : 0.01f * s1;
                    v[e] = (short)f2bf(s0); v[4 + e] = (short)f2bf(s1);
                }
            } else if (k0 < 4096) {
                const f32x4* dp = (const f32x4*)(dist + (size_t)row * 2048 + (k0 - 2048));
                f32x4 f0 = dp[0], f1 = dp[1];
                #pragma unroll
                for (int e = 0; e < 4; ++e) { v[e] = (short)f2bf(f0[e]); v[4 + e] = (short)f2bf(f1[e]); }
            } else if (k0 < 4128) {
                const f32x4* pp = (const f32x4*)(pref + (size_t)row * P_DIM + (k0 - 4096));
                f32x4 f0 = pp[0], f1 = pp[1];
                #pragma unroll
                for (int e = 0; e < 4; ++e) { v[e] = (short)f2bf(f0[e]); v[4 + e] = (short)f2bf(f1[e]); }
            } else {
                #pragma unroll
                for (int e = 0; e < 8; ++e) v[e] = 0;
            }
            *(bf16x8*)&ta[r * 64 + ((c ^ (r & 7)) * 8)] = v;
        }
    }
}

// ---------------- 64x64-tile DMA GEMM: 4 blocks/CU TLP + XCD-chunked swizzle (r7-frozen) ----------------
// Co-bound by TCP staging BW (~26 us floor) + LDS port; alternative geometries lose more to
// latency (1 blk/CU) -- measured across r0/r2/r3/r4/r5/r8/r9. Fused epilogue adds.
__global__ __launch_bounds__(256, 4) void k_gemm_d(const u16* __restrict__ Ap, const u16* __restrict__ Bp,
                                                   const float* __restrict__ cvec, const float* __restrict__ w3,
                                                   const float* __restrict__ keepf,
                                                   float* __restrict__ Cout) {
    __shared__ __attribute__((aligned(16))) short As[2][4096];   // 2 x 8 KB
    __shared__ __attribute__((aligned(16))) short Bs[2][4096];   // 2 x 8 KB
    int t = threadIdx.x;
    // bijective XCD-chunk decode: xcd = bid&7 (round-robin), chunk = 16mt x 8nt
    int b = blockIdx.x;                 // 0..1023
    int c = b & 7, u = b >> 3;          // chunk id, index within chunk
    int mt = (c & 1) * 16 + (u & 15);   // 0..31
    int nt = (c >> 1) * 8 + (u >> 4);   // 0..31
    int tileM = mt * 64, tileN = nt * 64;
    int lane = t & 63;
    int wid = t >> 6;                   // 0..3
    int waveM = wid & 1, waveN = wid >> 1;
    int l16 = lane & 15, quad = lane >> 4;

    f32x4 acc[2][2];
    #pragma unroll
    for (int a_ = 0; a_ < 2; ++a_)
        #pragma unroll
        for (int b_ = 0; b_ < 2; ++b_) acc[a_][b_] = (f32x4){0.f, 0.f, 0.f, 0.f};

    // A: strip mt (64 rows), 4096 u16 per kt.  B: 64-row half of 128-row strip nt>>1.
    const u16* gA = Ap + ((size_t)mt * NKT) * 4096 + t * 8;
    const u16* gB = Bp + ((size_t)(nt >> 1) * NKT) * 8192 + (nt & 1) * 4096 + t * 8;

#define ISSUE(ktv, bb) do { \
        const u16* a0 = gA + (size_t)(ktv) * 4096; \
        const u16* b0 = gB + (size_t)(ktv) * 8192; \
        u16* ad = (u16*)As[bb] + t * 8; \
        u16* bd = (u16*)Bs[bb] + t * 8; \
        gload16(a0, ad); \
        gload16(a0 + 2048, ad + 2048); \
        gload16(b0, bd); \
        gload16(b0 + 2048, bd + 2048); \
    } while (0)

    ISSUE(0, 0);   // preload kt=0 into buffer 0

    int cur = 0;
    for (int kt = 0; kt < NKT; ++kt) {
        __syncthreads();   // drains this tile's DMA (issued a full MFMA phase ago, except kt=0)
        if (kt + 1 < NKT) ISSUE(kt + 1, cur ^ 1);
        const short* Asc = As[cur];
        const short* Bsc = Bs[cur];
        #pragma unroll
        for (int kk = 0; kk < 64; kk += 32) {
            int cbase = kk >> 3;
            bf16x8 af[2], bfr[2];
            #pragma unroll
            for (int mi = 0; mi < 2; ++mi) {
                int row = waveM * 32 + mi * 16 + l16;
                af[mi] = *(const bf16x8*)&Asc[SWZ(row, cbase + quad)];
            }
            #pragma unroll
            for (int ni = 0; ni < 2; ++ni) {
                int row = waveN * 32 + ni * 16 + l16;
                bfr[ni] = *(const bf16x8*)&Bsc[SWZ(row, cbase + quad)];
            }
            #pragma unroll
            for (int mi = 0; mi < 2; ++mi)
                #pragma unroll
                for (int ni = 0; ni < 2; ++ni)
                    acc[mi][ni] = __builtin_amdgcn_mfma_f32_16x16x32_bf16(af[mi], bfr[ni], acc[mi][ni], 0, 0, 0);
        }
        cur ^= 1;
    }
#undef ISSUE
    #pragma unroll
    for (int mi = 0; mi < 2; ++mi)
        #pragma unroll
        for (int ni = 0; ni < 2; ++ni) {
            int row0 = tileM + waveM * 32 + mi * 16 + quad * 4;
            int col = tileN + waveN * 32 + ni * 16 + l16;
            float cv = cvec[col], wv = w3[col];
            float* cp = Cout + (size_t)row0 * N_NODES + col;
            #pragma unroll
            for (int rr = 0; rr < 4; ++rr)
                cp[(size_t)rr * N_NODES] = acc[mi][ni][rr] + cv + keepf[row0 + rr] * wv;
        }
}

// ---------------- epilogue: pure in-place log-softmax (adds fused into GEMM) ----------------
__global__ __launch_bounds__(256) void k_epi(float* __restrict__ out) {
    int i = blockIdx.x, t = threadIdx.x;
    __shared__ float redmax[4], redsum[4];
    f32x4* orow = (f32x4*)(out + (size_t)i * N_NODES);
    f32x4 v0 = orow[t];
    f32x4 v1 = orow[t + 256];
    float vmax = fmaxf(fmaxf(fmaxf(v0[0], v0[1]), fmaxf(v0[2], v0[3])),
                       fmaxf(fmaxf(v1[0], v1[1]), fmaxf(v1[2], v1[3])));
    #pragma unroll
    for (int off = 32; off; off >>= 1) vmax = fmaxf(vmax, __shfl_xor(vmax, off, 64));
    if ((t & 63) == 0) redmax[t >> 6] = vmax;
    __syncthreads();
    vmax = fmaxf(fmaxf(redmax[0], redmax[1]), fmaxf(redmax[2], redmax[3]));
    float se = 0.f;
    #pragma unroll
    for (int e = 0; e < 4; ++e) se += expf(v0[e] - vmax) + expf(v1[e] - vmax);
    #pragma unroll
    for (int off = 32; off; off >>= 1) se += __shfl_xor(se, off, 64);
    if ((t & 63) == 0) redsum[t >> 6] = se;
    __syncthreads();
    se = redsum[0] + redsum[1] + redsum[2] + redsum[3];
    float lz = vmax + logf(se);
    orow[t] = v0 - lz;
    orow[t + 256] = v1 - lz;
}

extern "C" void kernel_launch(void* const* d_in, const int* in_sizes, int n_in,
                              void* d_out, int out_size, void* d_ws, size_t ws_size,
                              hipStream_t stream) {
    const float* dist    = (const float*)d_in[0];
    const float* emb     = (const float*)d_in[1];
    const float* lin_l_w = (const float*)d_in[2];
    const float* lin_l_b = (const float*)d_in[3];
    const float* lin_r_w = (const float*)d_in[4];
    const float* edge_w  = (const float*)d_in[5];
    const float* edge_b  = (const float*)d_in[6];
    const float* comb_w  = (const float*)d_in[7];
    const float* comb_b  = (const float*)d_in[8];
    const int* stops     = (const int*)d_in[9];
    const int* wk        = (const int*)d_in[10];
    const int* vh        = (const int*)d_in[11];

    // ws layout: 34.4 MB (budget >= 35.43 MB)
    char* ws = (char*)d_ws;
    float* pref  = (float*)(ws + 0);          // 262144
    float* av    = (float*)(ws + 262144);     // 8192
    float* bv    = (float*)(ws + 270336);     // 8192
    float* cvec  = (float*)(ws + 278528);     // 8192
    float* w3    = (float*)(ws + 286720);     // 8192
    float* keepf = (float*)(ws + 294912);     // 8192
    u16*   Ap    = (u16*)(ws + 303104);       // 17039360 -> 17342464
    u16*   Bp    = (u16*)(ws + 17342464);     // 17039360 -> 34381824
    float* out   = (float*)d_out;             // f32 [2048,2048]

    hipLaunchKernelGGL(k_aggpref, dim3(256),    dim3(256), 0, stream, emb, stops,
                       lin_l_w, lin_l_b, lin_r_w, edge_w, pref, av, bv, keepf);
    hipLaunchKernelGGL(k_pack,    dim3(65, 48), dim3(256), 0, stream, comb_w, comb_b, wk, vh,
                       dist, pref, av, bv, edge_b, Bp, Ap, cvec, w3);
    hipLaunchKernelGGL(k_gemm_d,  dim3(1024),   dim3(256), 0, stream, Ap, Bp, cvec, w3, keepf, out);
    hipLaunchKernelGGL(k_epi,     dim3(2048),   dim3(256), 0, stream, out);
}

// Round 11
// 175.684 us; speedup vs baseline: 1.1311x; 1.0520x over previous
//
#include <hip/hip_runtime.h>

typedef unsigned short u16;
typedef __attribute__((ext_vector_type(8))) short bf16x8;
typedef __attribute__((ext_vector_type(4))) float f32x4;

// round-to-nearest (ties away): 2 VALU ops
__device__ __forceinline__ u16 f2bf(float f) {
    return (u16)((__float_as_uint(f) + 0x8000u) >> 16);
}

#define N_NODES 2048
#define D_EMB 64
#define P_DIM 32
#define NS_STOPS 512
#define IN_LEN 4131   // 32 + 2048 + 2048 + 3
#define NKT 65        // K-tiles of 64 (2048 es + 2048 dist + 32 pref + 32 pad)

// 16B-chunk XOR swizzle within a tile row (8 chunks of 8 shorts)
#define SWZ(row, c) ((((row) * 8) + ((c) ^ ((row) & 7))) * 8)

__device__ __forceinline__ void gload16(const u16* g, u16* l) {
    __builtin_amdgcn_global_load_lds((const __attribute__((address_space(1))) void*)g,
                                     (__attribute__((address_space(3))) void*)l, 16, 0, 0);
}

// ---------------- k_front: aggpref (blocks 0..255) || B-pack (256..1295) || A-dist pack (1296..2319) ----------------
// B-pack and A-dist-pack have NO dependence on aggpref -> run concurrently, filling the CUs
// that aggpref's 256 blocks (1/CU) leave idle.
__global__ __launch_bounds__(256) void k_front(const float* __restrict__ emb, const int* __restrict__ stops,
                                               const float* __restrict__ lin_l_w, const float* __restrict__ lin_l_b,
                                               const float* __restrict__ lin_r_w, const float* __restrict__ edge_w,
                                               const float* __restrict__ comb_w, const float* __restrict__ comb_b,
                                               const int* __restrict__ wk_p, const int* __restrict__ vh_p,
                                               const float* __restrict__ dist,
                                               float* __restrict__ pref, float* __restrict__ av, float* __restrict__ bv,
                                               float* __restrict__ keepf,
                                               u16* __restrict__ Bp, u16* __restrict__ Ap,
                                               float* __restrict__ cvec, float* __restrict__ w3) {
    __shared__ int bm[64];
    __shared__ int kl[NS_STOPS];
    __shared__ float xiS[8][D_EMB];
    __shared__ float aggS[8][D_EMB];
    __shared__ float niS[8];
    __shared__ int degS[8];
    __shared__ int kiS[8];
    __shared__ int cnt;
    int t = threadIdx.x;
    int b = blockIdx.x;
    if (b < 256) {
        // ======== aggpref: 8 nodes per block, unstaged (emb L2-resident) ========
        int i0 = b * 8;
        if (t < 64) bm[t] = 0;
        if (t == 0) cnt = 0;
        if (t < 8) degS[t] = 0;
        ((float*)aggS)[t] = 0.f;
        ((float*)aggS)[t + 256] = 0.f;
        __syncthreads();
        {   // scatter stops into bitmap
            int s0 = stops[t], s1 = stops[t + 256];
            atomicOr(&bm[s0 >> 5], 1 << (s0 & 31));
            atomicOr(&bm[s1 >> 5], 1 << (s1 & 31));
        }
        __syncthreads();
        {   // compact set nodes into kl
            int w = bm[t >> 2];
            int base = (t >> 2) * 32 + (t & 3) * 8;
            #pragma unroll
            for (int e = 0; e < 8; ++e)
                if ((w >> ((t & 3) * 8 + e)) & 1) { int p = atomicAdd(&cnt, 1); kl[p] = base + e; }
        }
        if (t < 8) { int i = i0 + t; kiS[t] = (bm[i >> 5] >> (i & 31)) & 1; }
        {   // load this block's 8 node rows
            int n = t >> 5, d = (t & 31) * 2;
            xiS[n][d]     = emb[(i0 + n) * D_EMB + d];
            xiS[n][d + 1] = emb[(i0 + n) * D_EMB + d + 1];
        }
        __syncthreads();
        if (t < 8) {
            float s = 0.f;
            #pragma unroll
            for (int d = 0; d < D_EMB; ++d) s += xiS[t][d] * xiS[t][d];
            niS[t] = fmaxf(sqrtf(s), 1e-8f);
        }
        __syncthreads();
        int nk = cnt;
        for (int u = t; u < nk; u += 256) {
            int j = kl[u];
            const f32x4* ej = (const f32x4*)&emb[j * D_EMB];
            f32x4 er[16];
            f32x4 sv = {0.f, 0.f, 0.f, 0.f};
            #pragma unroll
            for (int d = 0; d < 16; ++d) { er[d] = ej[d]; sv += er[d] * er[d]; }
            float nj = fmaxf(sqrtf(sv[0] + sv[1] + sv[2] + sv[3]), 1e-8f);
            #pragma unroll
            for (int n = 0; n < 8; ++n) {
                if (!kiS[n] || j == i0 + n) continue;
                f32x4 dv = {0.f, 0.f, 0.f, 0.f};
                #pragma unroll
                for (int d = 0; d < 16; ++d) dv += (*(const f32x4*)&xiS[n][d * 4]) * er[d];
                float dot = dv[0] + dv[1] + dv[2] + dv[3];
                if (dot > 0.5f * niS[n] * nj) {
                    atomicAdd(&degS[n], 1);
                    #pragma unroll
                    for (int d = 0; d < 16; ++d) {
                        atomicAdd(&aggS[n][d * 4 + 0], er[d][0]);
                        atomicAdd(&aggS[n][d * 4 + 1], er[d][1]);
                        atomicAdd(&aggS[n][d * 4 + 2], er[d][2]);
                        atomicAdd(&aggS[n][d * 4 + 3], er[d][3]);
                    }
                }
            }
        }
        __syncthreads();
        {   // finish: n = t>>5 node, p = t&31 pref dim
            int n = t >> 5, p = t & 31;
            int i = i0 + n;
            float inv = kiS[n] ? (1.f / fmaxf((float)degS[n], 1.0f)) : 0.f;
            float s = lin_l_b[p];
            const float* wl = &lin_l_w[p * D_EMB];
            const float* wr = &lin_r_w[p * D_EMB];
            #pragma unroll
            for (int d = 0; d < D_EMB; ++d) s += aggS[n][d] * inv * wl[d] + xiS[n][d] * wr[d];
            pref[i * P_DIM + p] = s;
            float a = s * edge_w[p];
            float bb = s * edge_w[P_DIM + p];
            #pragma unroll
            for (int off = 16; off; off >>= 1) { a += __shfl_xor(a, off, 32); bb += __shfl_xor(bb, off, 32); }
            if (p == 0) { av[i] = a; bv[i] = bb; keepf[i] = (float)kiS[n]; }
        }
    } else if (b < 1296) {
        // ======== B-pack: 128 rows x 64 cols of comb_w -> Bp[nt][kt] (independent of aggpref) ========
        int bq = b - 256;
        int nt = bq / 65, kt = bq % 65;
        u16* tb = Bp + ((size_t)nt * NKT + kt) * 8192;
        #pragma unroll
        for (int it = 0; it < 4; ++it) {
            int q = t + it * 256;
            int r = q >> 3, c = q & 7;
            int j = nt * 128 + r;
            int k0 = kt * 64 + c * 8;
            const float* cw = comb_w + (size_t)j * IN_LEN;
            bf16x8 v;
            if (k0 < 4096) {
                f32x4 f0, f1;
                __builtin_memcpy(&f0, cw + 32 + k0, 16);
                __builtin_memcpy(&f1, cw + 36 + k0, 16);
                #pragma unroll
                for (int e = 0; e < 4; ++e) { v[e] = (short)f2bf(f0[e]); v[4 + e] = (short)f2bf(f1[e]); }
            } else if (k0 < 4128) {
                f32x4 f0, f1;
                __builtin_memcpy(&f0, cw + (k0 - 4096), 16);
                __builtin_memcpy(&f1, cw + (k0 - 4092), 16);
                #pragma unroll
                for (int e = 0; e < 4; ++e) { v[e] = (short)f2bf(f0[e]); v[4 + e] = (short)f2bf(f1[e]); }
            } else {
                #pragma unroll
                for (int e = 0; e < 8; ++e) v[e] = 0;
            }
            *(bf16x8*)&tb[r * 64 + ((c ^ (r & 7)) * 8)] = v;
        }
        if (kt == 64 && t < 128) {   // cvec/w3 once per row (independent of aggpref)
            int j = nt * 128 + t;
            const float* cw = comb_w + (size_t)j * IN_LEN;
            float wk = (float)wk_p[0], vh = (float)vh_p[0];
            cvec[j] = wk * cw[4128] + vh * cw[4129] + comb_b[j];
            w3[j] = cw[4130];
        }
    } else {
        // ======== A-dist pack: kt 32..63 (dist region, independent of aggpref) ========
        int bq = b - 1296;
        int rt = bq >> 5, kt = 32 + (bq & 31);
        u16* ta = Ap + ((size_t)rt * NKT + kt) * 4096;
        #pragma unroll
        for (int it = 0; it < 2; ++it) {
            int q = t + it * 256;
            int r = q >> 3, c = q & 7;
            int row = rt * 64 + r;
            int k0 = kt * 64 + c * 8;
            const f32x4* dp = (const f32x4*)(dist + (size_t)row * 2048 + (k0 - 2048));
            f32x4 f0 = dp[0], f1 = dp[1];
            bf16x8 v;
            #pragma unroll
            for (int e = 0; e < 4; ++e) { v[e] = (short)f2bf(f0[e]); v[4 + e] = (short)f2bf(f1[e]); }
            *(bf16x8*)&ta[r * 64 + ((c ^ (r & 7)) * 8)] = v;
        }
    }
}

// ---------------- k_packA2: av/bv/pref-dependent A tiles (kt 0..31 es, kt 64 pref/pad) ----------------
__global__ __launch_bounds__(256) void k_packA2(const float* __restrict__ pref,
                                                const float* __restrict__ av, const float* __restrict__ bv,
                                                const float* __restrict__ edge_b,
                                                u16* __restrict__ Ap) {
    int b = blockIdx.x;          // 0..1055 = 32 rt x 33 kti
    int rt = b / 33, kti = b % 33;
    int kt = (kti < 32) ? kti : 64;
    int t = threadIdx.x;
    u16* ta = Ap + ((size_t)rt * NKT + kt) * 4096;
    float eb = edge_b[0];
    #pragma unroll
    for (int it = 0; it < 2; ++it) {
        int q = t + it * 256;
        int r = q >> 3, c = q & 7;
        int row = rt * 64 + r;
        int k0 = kt * 64 + c * 8;
        bf16x8 v;
        if (k0 < 2048) {                 // es region: leaky(av[row] + bv[col] + eb)
            float ab = av[row] + eb;
            f32x4 f0 = *(const f32x4*)(bv + k0);
            f32x4 f1 = *(const f32x4*)(bv + k0 + 4);
            #pragma unroll
            for (int e = 0; e < 4; ++e) {
                float s0 = ab + f0[e]; s0 = (s0 >= 0.f) ? s0 : 0.01f * s0;
                float s1 = ab + f1[e]; s1 = (s1 >= 0.f) ? s1 : 0.01f * s1;
                v[e] = (short)f2bf(s0); v[4 + e] = (short)f2bf(s1);
            }
        } else if (k0 < 4128) {          // pref region (k0 4096..4127)
            const f32x4* pp = (const f32x4*)(pref + (size_t)row * P_DIM + (k0 - 4096));
            f32x4 f0 = pp[0], f1 = pp[1];
            #pragma unroll
            for (int e = 0; e < 4; ++e) { v[e] = (short)f2bf(f0[e]); v[4 + e] = (short)f2bf(f1[e]); }
        } else {
            #pragma unroll
            for (int e = 0; e < 8; ++e) v[e] = 0;
        }
        *(bf16x8*)&ta[r * 64 + ((c ^ (r & 7)) * 8)] = v;
    }
}

// ---------------- 64x64-tile DMA GEMM: 4 blocks/CU TLP + XCD-chunked swizzle (frozen, r7/r10) ----------------
// Co-bound by TCP staging BW + LDS port; measured floor ~53.5 us across 6 structural variants.
// Fused epilogue: C += cvec[col] + keepf[row]*w3[col].
__global__ __launch_bounds__(256, 4) void k_gemm_d(const u16* __restrict__ Ap, const u16* __restrict__ Bp,
                                                   const float* __restrict__ cvec, const float* __restrict__ w3,
                                                   const float* __restrict__ keepf,
                                                   float* __restrict__ Cout) {
    __shared__ __attribute__((aligned(16))) short As[2][4096];   // 2 x 8 KB
    __shared__ __attribute__((aligned(16))) short Bs[2][4096];   // 2 x 8 KB
    int t = threadIdx.x;
    // bijective XCD-chunk decode: xcd = bid&7 (round-robin), chunk = 16mt x 8nt
    int b = blockIdx.x;                 // 0..1023
    int c = b & 7, u = b >> 3;          // chunk id, index within chunk
    int mt = (c & 1) * 16 + (u & 15);   // 0..31
    int nt = (c >> 1) * 8 + (u >> 4);   // 0..31
    int tileM = mt * 64, tileN = nt * 64;
    int lane = t & 63;
    int wid = t >> 6;                   // 0..3
    int waveM = wid & 1, waveN = wid >> 1;
    int l16 = lane & 15, quad = lane >> 4;

    f32x4 acc[2][2];
    #pragma unroll
    for (int a_ = 0; a_ < 2; ++a_)
        #pragma unroll
        for (int b_ = 0; b_ < 2; ++b_) acc[a_][b_] = (f32x4){0.f, 0.f, 0.f, 0.f};

    // A: strip mt (64 rows), 4096 u16 per kt.  B: 64-row half of 128-row strip nt>>1.
    const u16* gA = Ap + ((size_t)mt * NKT) * 4096 + t * 8;
    const u16* gB = Bp + ((size_t)(nt >> 1) * NKT) * 8192 + (nt & 1) * 4096 + t * 8;

#define ISSUE(ktv, bb) do { \
        const u16* a0 = gA + (size_t)(ktv) * 4096; \
        const u16* b0 = gB + (size_t)(ktv) * 8192; \
        u16* ad = (u16*)As[bb] + t * 8; \
        u16* bd = (u16*)Bs[bb] + t * 8; \
        gload16(a0, ad); \
        gload16(a0 + 2048, ad + 2048); \
        gload16(b0, bd); \
        gload16(b0 + 2048, bd + 2048); \
    } while (0)

    ISSUE(0, 0);   // preload kt=0 into buffer 0

    int cur = 0;
    for (int kt = 0; kt < NKT; ++kt) {
        __syncthreads();   // drains this tile's DMA (issued a full MFMA phase ago, except kt=0)
        if (kt + 1 < NKT) ISSUE(kt + 1, cur ^ 1);
        const short* Asc = As[cur];
        const short* Bsc = Bs[cur];
        #pragma unroll
        for (int kk = 0; kk < 64; kk += 32) {
            int cbase = kk >> 3;
            bf16x8 af[2], bfr[2];
            #pragma unroll
            for (int mi = 0; mi < 2; ++mi) {
                int row = waveM * 32 + mi * 16 + l16;
                af[mi] = *(const bf16x8*)&Asc[SWZ(row, cbase + quad)];
            }
            #pragma unroll
            for (int ni = 0; ni < 2; ++ni) {
                int row = waveN * 32 + ni * 16 + l16;
                bfr[ni] = *(const bf16x8*)&Bsc[SWZ(row, cbase + quad)];
            }
            #pragma unroll
            for (int mi = 0; mi < 2; ++mi)
                #pragma unroll
                for (int ni = 0; ni < 2; ++ni)
                    acc[mi][ni] = __builtin_amdgcn_mfma_f32_16x16x32_bf16(af[mi], bfr[ni], acc[mi][ni], 0, 0, 0);
        }
        cur ^= 1;
    }
#undef ISSUE
    #pragma unroll
    for (int mi = 0; mi < 2; ++mi)
        #pragma unroll
        for (int ni = 0; ni < 2; ++ni) {
            int row0 = tileM + waveM * 32 + mi * 16 + quad * 4;
            int col = tileN + waveN * 32 + ni * 16 + l16;
            float cv = cvec[col], wv = w3[col];
            float* cp = Cout + (size_t)row0 * N_NODES + col;
            #pragma unroll
            for (int rr = 0; rr < 4; ++rr)
                cp[(size_t)rr * N_NODES] = acc[mi][ni][rr] + cv + keepf[row0 + rr] * wv;
        }
}

// ---------------- epilogue: pure in-place log-softmax (adds fused into GEMM) ----------------
__global__ __launch_bounds__(256) void k_epi(float* __restrict__ out) {
    int i = blockIdx.x, t = threadIdx.x;
    __shared__ float redmax[4], redsum[4];
    f32x4* orow = (f32x4*)(out + (size_t)i * N_NODES);
    f32x4 v0 = orow[t];
    f32x4 v1 = orow[t + 256];
    float vmax = fmaxf(fmaxf(fmaxf(v0[0], v0[1]), fmaxf(v0[2], v0[3])),
                       fmaxf(fmaxf(v1[0], v1[1]), fmaxf(v1[2], v1[3])));
    #pragma unroll
    for (int off = 32; off; off >>= 1) vmax = fmaxf(vmax, __shfl_xor(vmax, off, 64));
    if ((t & 63) == 0) redmax[t >> 6] = vmax;
    __syncthreads();
    vmax = fmaxf(fmaxf(redmax[0], redmax[1]), fmaxf(redmax[2], redmax[3]));
    float se = 0.f;
    #pragma unroll
    for (int e = 0; e < 4; ++e) se += expf(v0[e] - vmax) + expf(v1[e] - vmax);
    #pragma unroll
    for (int off = 32; off; off >>= 1) se += __shfl_xor(se, off, 64);
    if ((t & 63) == 0) redsum[t >> 6] = se;
    __syncthreads();
    se = redsum[0] + redsum[1] + redsum[2] + redsum[3];
    float lz = vmax + logf(se);
    orow[t] = v0 - lz;
    orow[t + 256] = v1 - lz;
}

extern "C" void kernel_launch(void* const* d_in, const int* in_sizes, int n_in,
                              void* d_out, int out_size, void* d_ws, size_t ws_size,
                              hipStream_t stream) {
    const float* dist    = (const float*)d_in[0];
    const float* emb     = (const float*)d_in[1];
    const float* lin_l_w = (const float*)d_in[2];
    const float* lin_l_b = (const float*)d_in[3];
    const float* lin_r_w = (const float*)d_in[4];
    const float* edge_w  = (const float*)d_in[5];
    const float* edge_b  = (const float*)d_in[6];
    const float* comb_w  = (const float*)d_in[7];
    const float* comb_b  = (const float*)d_in[8];
    const int* stops     = (const int*)d_in[9];
    const int* wk        = (const int*)d_in[10];
    const int* vh        = (const int*)d_in[11];

    // ws layout: 34.4 MB (budget >= 35.43 MB)
    char* ws = (char*)d_ws;
    float* pref  = (float*)(ws + 0);          // 262144
    float* av    = (float*)(ws + 262144);     // 8192
    float* bv    = (float*)(ws + 270336);     // 8192
    float* cvec  = (float*)(ws + 278528);     // 8192
    float* w3    = (float*)(ws + 286720);     // 8192
    float* keepf = (float*)(ws + 294912);     // 8192
    u16*   Ap    = (u16*)(ws + 303104);       // 17039360 -> 17342464
    u16*   Bp    = (u16*)(ws + 17342464);     // 17039360 -> 34381824
    float* out   = (float*)d_out;             // f32 [2048,2048]

    hipLaunchKernelGGL(k_front,  dim3(2320), dim3(256), 0, stream, emb, stops,
                       lin_l_w, lin_l_b, lin_r_w, edge_w, comb_w, comb_b, wk, vh,
                       dist, pref, av, bv, keepf, Bp, Ap, cvec, w3);
    hipLaunchKernelGGL(k_packA2, dim3(1056), dim3(256), 0, stream, pref, av, bv, edge_b, Ap);
    hipLaunchKernelGGL(k_gemm_d, dim3(1024), dim3(256), 0, stream, Ap, Bp, cvec, w3, keepf, out);
    hipLaunchKernelGGL(k_epi,    dim3(2048), dim3(256), 0, stream, out);
}